// Round 1
// baseline (494.791 us; speedup 1.0000x reference)
//
#include <hip/hip_runtime.h>

// DST-I spectral Helmholtz solver, NZ=4, NX=NY=2048.
// psi = Cm2l · [ S (S (Cl2m·q) S ⊘ H) S  + alpha·homsol ],  S = DST-I matrix (symmetric, orthonormal)
// All big matmuls are C = A·S with S symmetric -> B^T tiles == S row tiles (same staging as A).

typedef __attribute__((ext_vector_type(8))) short bf16x8;
typedef __attribute__((ext_vector_type(4))) float f32x4;
typedef __attribute__((ext_vector_type(8))) unsigned short ushort8;

#define LDS_SPACE __attribute__((address_space(3)))
#define GLB_SPACE __attribute__((address_space(1)))

__device__ __forceinline__ void gld_lds16(const unsigned short* g, unsigned short* l) {
  __builtin_amdgcn_global_load_lds((const GLB_SPACE void*)g, (LDS_SPACE void*)l, 16, 0, 0);
}

__device__ __forceinline__ unsigned short f2b(float f) {
  union { float f; unsigned u; } v; v.f = f;
  unsigned r = (v.u + 0x7fffu + ((v.u >> 16) & 1u)) >> 16;  // RNE
  return (unsigned short)r;
}
__device__ __forceinline__ float b2f(unsigned short u) {
  union { unsigned u; float f; } v; v.u = ((unsigned)u) << 16;
  return v.f;
}

// ---- DST-I matrix, padded to 2048x2048 (row/col 2047 zero), bf16 ----
__global__ __launch_bounds__(256)
void dst_kernel(unsigned short* __restrict__ Sb) {
  const int idx = blockIdx.x * 256 + threadIdx.x;     // < 2048*2048
  const int j = idx & 2047, i = idx >> 11;
  float v = 0.f;
  if (i < 2047 && j < 2047) {
    const int ph = ((i + 1) * (j + 1)) & 4095;        // exact phase mod 2*pi
    v = 0.03125f * sinf(3.14159265358979323846f * (float)ph * (1.0f / 2048.0f));
  }
  Sb[idx] = f2b(v);
}

// ---- layer->mode mix: P[m] = sum_l Cl2m[m,l] q[l], padded to 2048^2, bf16 ----
__global__ __launch_bounds__(256)
void mix_kernel(const float* __restrict__ q, const float* __restrict__ Cl2m,
                unsigned short* __restrict__ P) {
  const int idx = blockIdx.x * 256 + threadIdx.x;     // < 2048*2048
  const int y = idx & 2047, x = idx >> 11;
  float c[16];
#pragma unroll
  for (int i = 0; i < 16; ++i) c[i] = Cl2m[i];
  float v0 = 0.f, v1 = 0.f, v2 = 0.f, v3 = 0.f;
  if (x < 2047 && y < 2047) {
    const size_t o = (size_t)x * 2047 + y;
    const float q0 = q[o];
    const float q1 = q[o + 4190209u];
    const float q2 = q[o + 2u * 4190209u];
    const float q3 = q[o + 3u * 4190209u];
    v0 = c[0]  * q0 + c[1]  * q1 + c[2]  * q2 + c[3]  * q3;
    v1 = c[4]  * q0 + c[5]  * q1 + c[6]  * q2 + c[7]  * q3;
    v2 = c[8]  * q0 + c[9]  * q1 + c[10] * q2 + c[11] * q3;
    v3 = c[12] * q0 + c[13] * q1 + c[14] * q2 + c[15] * q3;
  }
  P[idx]                = f2b(v0);
  P[idx + 4194304u]     = f2b(v1);
  P[idx + 2u * 4194304u] = f2b(v2);
  P[idx + 3u * 4194304u] = f2b(v3);
}

// ---- batched per-mode 2048x2048 bf16 transpose (64x64 LDS tiles) ----
__global__ __launch_bounds__(256)
void transpose_bf16(const unsigned short* __restrict__ in, unsigned short* __restrict__ out) {
  __shared__ unsigned short tile[64][65];
  const size_t pb = (size_t)blockIdx.z * (2048u * 2048u);
  const unsigned short* ip = in + pb;
  unsigned short* op = out + pb;
  const int r0 = blockIdx.y * 64, c0 = blockIdx.x * 64;
  const int t = threadIdx.x;
  const int rr = t >> 3;          // 0..31
  const int cc = (t & 7) * 8;     // 0..56
#pragma unroll
  for (int ch = 0; ch < 2; ++ch) {
    const int r = ch * 32 + rr;
    ushort8 v = *(const ushort8*)&ip[(size_t)(r0 + r) * 2048 + c0 + cc];
#pragma unroll
    for (int j = 0; j < 8; ++j) tile[r][cc + j] = v[j];
  }
  __syncthreads();
#pragma unroll
  for (int ch = 0; ch < 2; ++ch) {
    const int r = ch * 32 + rr;
    ushort8 v;
#pragma unroll
    for (int j = 0; j < 8; ++j) v[j] = tile[cc + j][r];
    *(ushort8*)&op[(size_t)(c0 + r) * 2048 + r0 + cc] = v;
  }
}

// ---- GEMM: C[8192x2048] = A[8192x2048] * S (S symmetric 2048^2), bf16 in, f32 acc ----
// EPI 0: write bf16. EPI 1: divide by H (interior), write bf16. EPI 2: write bf16 + per-mode sum.
template <int EPI>
__global__ __launch_bounds__(256, 2)
void gemm_as(const unsigned short* __restrict__ A, const unsigned short* __restrict__ S,
             unsigned short* __restrict__ Cb, const float* __restrict__ H,
             float* __restrict__ sums) {
  __shared__ __align__(16) unsigned short As[128 * 32];
  __shared__ __align__(16) unsigned short Bs[128 * 32];
  const int bn = blockIdx.x, bm = blockIdx.y;
  const int tid = threadIdx.x, wave = tid >> 6, lane = tid & 63;
  const int wr = wave >> 1, wc = wave & 1;

  // staging: 8 chunks of 1KB per tile; wave w owns chunks 2w,2w+1; lane covers 16B
  const int srow = wave * 32 + (lane >> 2);       // row in tile for chunk0
  const int sk = (lane & 3) * 8;                  // k element offset
  const unsigned short* Ag0 = A + (size_t)(bm * 128 + srow) * 2048 + sk;
  const unsigned short* Ag1 = Ag0 + (size_t)16 * 2048;
  const unsigned short* Bg0 = S + (size_t)(bn * 128 + srow) * 2048 + sk;
  const unsigned short* Bg1 = Bg0 + (size_t)16 * 2048;
  unsigned short* AsC0 = As + wave * 1024;        // element offset (chunk=512 elems)
  unsigned short* AsC1 = AsC0 + 512;
  unsigned short* BsC0 = Bs + wave * 1024;
  unsigned short* BsC1 = BsC0 + 512;

  f32x4 acc[4][4] = {};
  const int lr = lane & 15, kg = lane >> 4;

  for (int k0 = 0; k0 < 2048; k0 += 32) {
    __syncthreads();
    gld_lds16(Ag0 + k0, AsC0);
    gld_lds16(Ag1 + k0, AsC1);
    gld_lds16(Bg0 + k0, BsC0);
    gld_lds16(Bg1 + k0, BsC1);
    __syncthreads();   // compiler drains vmcnt before s_barrier
    bf16x8 av[4], bv[4];
#pragma unroll
    for (int i = 0; i < 4; ++i)
      av[i] = *(const bf16x8*)&As[(wr * 64 + i * 16 + lr) * 32 + kg * 8];
#pragma unroll
    for (int i = 0; i < 4; ++i)
      bv[i] = *(const bf16x8*)&Bs[(wc * 64 + i * 16 + lr) * 32 + kg * 8];
#pragma unroll
    for (int mi = 0; mi < 4; ++mi)
#pragma unroll
      for (int ni = 0; ni < 4; ++ni)
        acc[mi][ni] = __builtin_amdgcn_mfma_f32_16x16x32_bf16(av[mi], bv[ni], acc[mi][ni], 0, 0, 0);
  }

  // epilogue: C[row = lane>>4*4+j, col = lane&15] per 16x16 fragment
  float s = 0.f;
#pragma unroll
  for (int mi = 0; mi < 4; ++mi) {
#pragma unroll
    for (int ni = 0; ni < 4; ++ni) {
      const int col = bn * 128 + wc * 64 + ni * 16 + lr;
#pragma unroll
      for (int j = 0; j < 4; ++j) {
        const int gr = bm * 128 + wr * 64 + mi * 16 + kg * 4 + j;
        const float v = acc[mi][ni][j];
        if (EPI == 1) {
          const int i = gr & 2047;
          float o = 0.f;
          if (i < 2047 && col < 2047)
            o = v / H[((size_t)(gr >> 11) * 2047 + i) * 2047 + col];
          Cb[(size_t)gr * 2048 + col] = f2b(o);
        } else {
          Cb[(size_t)gr * 2048 + col] = f2b(v);
          if (EPI == 2) s += v;
        }
      }
    }
  }
  if (EPI == 2) {
#pragma unroll
    for (int off = 32; off > 0; off >>= 1) s += __shfl_xor(s, off);
    if (lane == 0) atomicAdd(&sums[(bm * 128) >> 11], s);
  }
}

// ---- final: un-pad, homogeneous correction, mode->layer mix ----
__global__ __launch_bounds__(256)
void final_kernel(const unsigned short* __restrict__ T5, const float* __restrict__ homsol,
                  const float* __restrict__ hm, const float* __restrict__ Cm2l,
                  const float* __restrict__ sums, float* __restrict__ out) {
  const int p = blockIdx.x * 256 + threadIdx.x;
  if (p >= 2049 * 2049) return;
  const int x = p / 2049, y = p - x * 2049;
  const bool interior = (x >= 1) && (x <= 2047) && (y >= 1) && (y <= 2047);
  float pm[4];
#pragma unroll
  for (int m = 0; m < 4; ++m) {
    float inner = 0.f;
    if (interior) inner = b2f(T5[(size_t)m * 4194304u + (size_t)(x - 1) * 2048 + (y - 1)]);
    const float alpha = -(sums[m] * (1.0f / 4194304.0f)) / hm[m];
    pm[m] = inner + alpha * homsol[(size_t)m * 4198401u + p];
  }
#pragma unroll
  for (int l = 0; l < 4; ++l) {
    out[(size_t)l * 4198401u + p] =
        Cm2l[l * 4 + 0] * pm[0] + Cm2l[l * 4 + 1] * pm[1] +
        Cm2l[l * 4 + 2] * pm[2] + Cm2l[l * 4 + 3] * pm[3];
  }
}

extern "C" void kernel_launch(void* const* d_in, const int* in_sizes, int n_in,
                              void* d_out, int out_size, void* d_ws, size_t ws_size,
                              hipStream_t stream) {
  const float* q     = (const float*)d_in[0];   // [4,2047,2047]
  const float* Cl2m  = (const float*)d_in[1];   // [4,4]
  const float* Cm2l  = (const float*)d_in[2];   // [4,4]
  const float* H     = (const float*)d_in[3];   // [4,2047,2047]
  const float* hom   = (const float*)d_in[4];   // [4,2049,2049]
  const float* hmean = (const float*)d_in[5];   // [4]
  float* out = (float*)d_out;

  char* ws = (char*)d_ws;
  unsigned short* P  = (unsigned short*)ws;                    // 33,554,432 B
  unsigned short* Q  = (unsigned short*)(ws + 33554432u);      // 33,554,432 B
  unsigned short* Sb = (unsigned short*)(ws + 67108864u);      //  8,388,608 B
  float* sums        = (float*)(ws + 75497472u);               //        16 B

  dst_kernel<<<16384, 256, 0, stream>>>(Sb);
  mix_kernel<<<16384, 256, 0, stream>>>(q, Cl2m, P);
  hipMemsetAsync(sums, 0, 16, stream);

  const dim3 gg(16, 64);   // N-tiles x M-tiles (M = 4 modes * 2048)
  // Q1 = P * S            (DST along y)
  gemm_as<0><<<gg, 256, 0, stream>>>(P, Sb, Q, nullptr, nullptr);
  transpose_bf16<<<dim3(32, 32, 4), 256, 0, stream>>>(Q, P);
  // Q2 = (P * S) / H      (DST along x; result is q_hat^T, H symmetric)
  gemm_as<1><<<gg, 256, 0, stream>>>(P, Sb, Q, H, nullptr);
  // P2 = Q2 * S           (inverse DST step 1)
  gemm_as<0><<<gg, 256, 0, stream>>>(Q, Sb, P, nullptr, nullptr);
  transpose_bf16<<<dim3(32, 32, 4), 256, 0, stream>>>(P, Q);
  // T5 = Q3 * S (+ per-mode sum for mean correction)
  gemm_as<2><<<gg, 256, 0, stream>>>(Q, Sb, P, nullptr, sums);

  final_kernel<<<16401, 256, 0, stream>>>(P, hom, hmean, Cm2l, sums, out);
}

// Round 2
// 395.963 us; speedup vs baseline: 1.2496x; 1.2496x over previous
//
#include <hip/hip_runtime.h>

// DST-I spectral Helmholtz solver, NZ=4, NX=NY=2048.
// psi = Cm2l · [ S (S (Cl2m·q) S ⊘ H) S  + alpha·homsol ],  S = DST-I matrix (symmetric, orthonormal)
// GEMMs use the 256x256 8-wave counted-vmcnt schedule (T1..T5).

typedef __attribute__((ext_vector_type(8))) short bf16x8;
typedef __attribute__((ext_vector_type(4))) float f32x4;
typedef __attribute__((ext_vector_type(8))) unsigned short ushort8;

#define LDS_SPACE __attribute__((address_space(3)))
#define GLB_SPACE __attribute__((address_space(1)))

__device__ __forceinline__ void gld_lds16(const unsigned short* g, unsigned short* l) {
  __builtin_amdgcn_global_load_lds((const GLB_SPACE void*)g, (LDS_SPACE void*)l, 16, 0, 0);
}

__device__ __forceinline__ bf16x8 ds_read128(const void* p) {
  bf16x8 r;
  const LDS_SPACE char* lp = (const LDS_SPACE char*)p;
  asm volatile("ds_read_b128 %0, %1" : "=v"(r) : "v"(lp));
  return r;
}

__device__ __forceinline__ unsigned short f2b(float f) {
  union { float f; unsigned u; } v; v.f = f;
  unsigned r = (v.u + 0x7fffu + ((v.u >> 16) & 1u)) >> 16;  // RNE
  return (unsigned short)r;
}
__device__ __forceinline__ float b2f(unsigned short u) {
  union { unsigned u; float f; } v; v.u = ((unsigned)u) << 16;
  return v.f;
}

// ---- DST-I matrix, padded to 2048x2048 (row/col 2047 zero), bf16 ----
__global__ __launch_bounds__(256)
void dst_kernel(unsigned short* __restrict__ Sb) {
  const int idx = blockIdx.x * 256 + threadIdx.x;
  const int j = idx & 2047, i = idx >> 11;
  float v = 0.f;
  if (i < 2047 && j < 2047) {
    const int ph = ((i + 1) * (j + 1)) & 4095;  // exact phase mod 2*pi
    v = 0.03125f * sinf(3.14159265358979323846f * (float)ph * (1.0f / 2048.0f));
  }
  Sb[idx] = f2b(v);
}

// ---- layer->mode mix: P[m] = sum_l Cl2m[m,l] q[l], padded to 2048^2, bf16 ----
__global__ __launch_bounds__(256)
void mix_kernel(const float* __restrict__ q, const float* __restrict__ Cl2m,
                unsigned short* __restrict__ P) {
  const int idx = blockIdx.x * 256 + threadIdx.x;
  const int y = idx & 2047, x = idx >> 11;
  float c[16];
#pragma unroll
  for (int i = 0; i < 16; ++i) c[i] = Cl2m[i];
  float v0 = 0.f, v1 = 0.f, v2 = 0.f, v3 = 0.f;
  if (x < 2047 && y < 2047) {
    const size_t o = (size_t)x * 2047 + y;
    const float q0 = q[o];
    const float q1 = q[o + 4190209u];
    const float q2 = q[o + 2u * 4190209u];
    const float q3 = q[o + 3u * 4190209u];
    v0 = c[0]  * q0 + c[1]  * q1 + c[2]  * q2 + c[3]  * q3;
    v1 = c[4]  * q0 + c[5]  * q1 + c[6]  * q2 + c[7]  * q3;
    v2 = c[8]  * q0 + c[9]  * q1 + c[10] * q2 + c[11] * q3;
    v3 = c[12] * q0 + c[13] * q1 + c[14] * q2 + c[15] * q3;
  }
  P[idx]                 = f2b(v0);
  P[idx + 4194304u]      = f2b(v1);
  P[idx + 2u * 4194304u] = f2b(v2);
  P[idx + 3u * 4194304u] = f2b(v3);
}

// ---- batched per-mode 2048x2048 bf16 transpose (64x64 LDS tiles) ----
__global__ __launch_bounds__(256)
void transpose_bf16(const unsigned short* __restrict__ in, unsigned short* __restrict__ out) {
  __shared__ unsigned short tile[64][65];
  const size_t pb = (size_t)blockIdx.z * (2048u * 2048u);
  const unsigned short* ip = in + pb;
  unsigned short* op = out + pb;
  const int r0 = blockIdx.y * 64, c0 = blockIdx.x * 64;
  const int t = threadIdx.x;
  const int rr = t >> 3;
  const int cc = (t & 7) * 8;
#pragma unroll
  for (int ch = 0; ch < 2; ++ch) {
    const int r = ch * 32 + rr;
    ushort8 v = *(const ushort8*)&ip[(size_t)(r0 + r) * 2048 + c0 + cc];
#pragma unroll
    for (int j = 0; j < 8; ++j) tile[r][cc + j] = v[j];
  }
  __syncthreads();
#pragma unroll
  for (int ch = 0; ch < 2; ++ch) {
    const int r = ch * 32 + rr;
    ushort8 v;
#pragma unroll
    for (int j = 0; j < 8; ++j) v[j] = tile[cc + j][r];
    *(ushort8*)&op[(size_t)(c0 + r) * 2048 + r0 + cc] = v;
  }
}

// ---- GEMM: C[8192x2048] = A[8192x2048] * S (S symmetric), 256^2 tile, 8 waves ----
// EPI 0: write bf16. EPI 1: divide by H (interior), write bf16. EPI 2: write bf16 + per-mode sum.
#define MFMA_BF16 __builtin_amdgcn_mfma_f32_16x16x32_bf16

template <int EPI>
__global__ __launch_bounds__(512, 2)
void gemm256(const unsigned short* __restrict__ A, const unsigned short* __restrict__ S,
             unsigned short* __restrict__ Cb, const float* __restrict__ H,
             float* __restrict__ sums) {
  __shared__ __align__(16) char lds[131072];  // 2 buffers x (A 32KB + B 32KB)
  const int bid = blockIdx.x;
  const int swz = (bid & 7) * 32 + (bid >> 3);      // XCD-bijective (256 % 8 == 0)
  const int bm = swz >> 3, bn = swz & 7;
  const int tid = threadIdx.x;
  const int lane = tid & 63, wave = tid >> 6;
  const int wr = wave >> 2, wc = wave & 3;          // 2 x 4 wave grid
  const int lr = lane & 15, kg = lane >> 4;

  const unsigned short* gA = A + (size_t)bm * 256 * 2048;
  const unsigned short* gB = S + (size_t)bn * 256 * 2048;

  // staging geometry: physical 16B slot ps = tid + i*512; row = ps>>3;
  // global col16 = (ps&7) ^ (row&7)  (inverse of the read-side XOR swizzle)
  const int row0 = tid >> 3;
  const int slot = (tid & 7) ^ (row0 & 7);

  auto stage = [&](int kt, int c) {
    char* lc = lds + c * 65536;
    const size_t ko = (size_t)kt * 64 + slot * 8;
#pragma unroll
    for (int i = 0; i < 4; ++i)
      gld_lds16(gA + (size_t)(row0 + i * 64) * 2048 + ko,
                (unsigned short*)(lc + (tid + i * 512) * 16));
#pragma unroll
    for (int i = 0; i < 4; ++i)
      gld_lds16(gB + (size_t)(row0 + i * 64) * 2048 + ko,
                (unsigned short*)(lc + 32768 + (tid + i * 512) * 16));
  };

  f32x4 acc[8][4];
#pragma unroll
  for (int m = 0; m < 8; ++m)
#pragma unroll
    for (int n = 0; n < 4; ++n) acc[m][n] = (f32x4){0.f, 0.f, 0.f, 0.f};

  stage(0, 0);
  stage(1, 1);

  const int arow = wr * 128 + lr;   // + m*16
  const int brow = wc * 64 + lr;    // + n*16
  const int x7 = lr & 7;            // (row & 7) for all frag rows

  for (int t = 0; t < 32; ++t) {
    const char* la = lds + (t & 1) * 65536;
    const char* lb = la + 32768;
    if (t < 31) asm volatile("s_waitcnt vmcnt(8)" ::: "memory");
    else        asm volatile("s_waitcnt vmcnt(0)" ::: "memory");
    __builtin_amdgcn_s_barrier();

    bf16x8 al[4][2], ah[4][2], bl[2][2], bh[2][2];

    // ---- phase 1: quad (m0-3, n0-1); reads A-lo (8) + B-lo (4)
#pragma unroll
    for (int m = 0; m < 4; ++m)
#pragma unroll
      for (int ks = 0; ks < 2; ++ks)
        al[m][ks] = ds_read128(la + (arow + m * 16) * 128 + (((ks * 4 + kg) ^ x7) << 4));
#pragma unroll
    for (int n = 0; n < 2; ++n)
#pragma unroll
      for (int ks = 0; ks < 2; ++ks)
        bl[n][ks] = ds_read128(lb + (brow + n * 16) * 128 + (((ks * 4 + kg) ^ x7) << 4));
    asm volatile("s_waitcnt lgkmcnt(0)" ::: "memory");
    __builtin_amdgcn_sched_barrier(0);
    __builtin_amdgcn_s_setprio(1);
#pragma unroll
    for (int ks = 0; ks < 2; ++ks)
#pragma unroll
      for (int m = 0; m < 4; ++m)
#pragma unroll
        for (int n = 0; n < 2; ++n)
          acc[m][n] = MFMA_BF16(al[m][ks], bl[n][ks], acc[m][n], 0, 0, 0);
    __builtin_amdgcn_s_setprio(0);
    __builtin_amdgcn_s_barrier();

    // ---- phase 2: quad (m0-3, n2-3); reads B-hi (4)
#pragma unroll
    for (int n = 0; n < 2; ++n)
#pragma unroll
      for (int ks = 0; ks < 2; ++ks)
        bh[n][ks] = ds_read128(lb + (brow + (n + 2) * 16) * 128 + (((ks * 4 + kg) ^ x7) << 4));
    asm volatile("s_waitcnt lgkmcnt(0)" ::: "memory");
    __builtin_amdgcn_sched_barrier(0);
    __builtin_amdgcn_s_setprio(1);
#pragma unroll
    for (int ks = 0; ks < 2; ++ks)
#pragma unroll
      for (int m = 0; m < 4; ++m)
#pragma unroll
        for (int n = 0; n < 2; ++n)
          acc[m][n + 2] = MFMA_BF16(al[m][ks], bh[n][ks], acc[m][n + 2], 0, 0, 0);
    __builtin_amdgcn_s_setprio(0);
    __builtin_amdgcn_s_barrier();

    // ---- phase 3: quad (m4-7, n2-3); reads A-hi (8)
#pragma unroll
    for (int m = 0; m < 4; ++m)
#pragma unroll
      for (int ks = 0; ks < 2; ++ks)
        ah[m][ks] = ds_read128(la + (arow + (m + 4) * 16) * 128 + (((ks * 4 + kg) ^ x7) << 4));
    asm volatile("s_waitcnt lgkmcnt(0)" ::: "memory");
    __builtin_amdgcn_sched_barrier(0);
    __builtin_amdgcn_s_setprio(1);
#pragma unroll
    for (int ks = 0; ks < 2; ++ks)
#pragma unroll
      for (int m = 0; m < 4; ++m)
#pragma unroll
        for (int n = 0; n < 2; ++n)
          acc[m + 4][n + 2] = MFMA_BF16(ah[m][ks], bh[n][ks], acc[m + 4][n + 2], 0, 0, 0);
    __builtin_amdgcn_s_setprio(0);
    __builtin_amdgcn_s_barrier();

    // ---- phase 4: quad (m4-7, n0-1); no reads (ah, bl live)
    __builtin_amdgcn_s_setprio(1);
#pragma unroll
    for (int ks = 0; ks < 2; ++ks)
#pragma unroll
      for (int m = 0; m < 4; ++m)
#pragma unroll
        for (int n = 0; n < 2; ++n)
          acc[m + 4][n] = MFMA_BF16(ah[m][ks], bl[n][ks], acc[m + 4][n], 0, 0, 0);
    __builtin_amdgcn_s_setprio(0);
    __builtin_amdgcn_s_barrier();   // all waves done reading buf[t&1]

    if (t < 30) stage(t + 2, t & 1);  // prefetch 2 tiles ahead into freed buffer
  }

  // ---- epilogue: C row = kg*4+j within fragment, col = lr
  float ssum = 0.f;
#pragma unroll
  for (int m = 0; m < 8; ++m) {
#pragma unroll
    for (int n = 0; n < 4; ++n) {
      const int col = bn * 256 + wc * 64 + n * 16 + lr;
#pragma unroll
      for (int j = 0; j < 4; ++j) {
        const int gr = bm * 256 + wr * 128 + m * 16 + kg * 4 + j;
        const float v = acc[m][n][j];
        if (EPI == 1) {
          const int i = gr & 2047;
          float o = 0.f;
          if (i < 2047 && col < 2047)
            o = v / H[((size_t)(gr >> 11) * 2047 + i) * 2047 + col];
          Cb[(size_t)gr * 2048 + col] = f2b(o);
        } else {
          Cb[(size_t)gr * 2048 + col] = f2b(v);
          if (EPI == 2) ssum += v;
        }
      }
    }
  }
  if (EPI == 2) {
#pragma unroll
    for (int off = 32; off > 0; off >>= 1) ssum += __shfl_xor(ssum, off);
    if (lane == 0) atomicAdd(&sums[bm >> 3], ssum);
  }
}

// ---- final: un-pad, homogeneous correction, mode->layer mix ----
__global__ __launch_bounds__(256)
void final_kernel(const unsigned short* __restrict__ T5, const float* __restrict__ homsol,
                  const float* __restrict__ hm, const float* __restrict__ Cm2l,
                  const float* __restrict__ sums, float* __restrict__ out) {
  const int p = blockIdx.x * 256 + threadIdx.x;
  if (p >= 2049 * 2049) return;
  const int x = p / 2049, y = p - x * 2049;
  const bool interior = (x >= 1) && (x <= 2047) && (y >= 1) && (y <= 2047);
  float pm[4];
#pragma unroll
  for (int m = 0; m < 4; ++m) {
    float inner = 0.f;
    if (interior) inner = b2f(T5[(size_t)m * 4194304u + (size_t)(x - 1) * 2048 + (y - 1)]);
    const float alpha = -(sums[m] * (1.0f / 4194304.0f)) / hm[m];
    pm[m] = inner + alpha * homsol[(size_t)m * 4198401u + p];
  }
#pragma unroll
  for (int l = 0; l < 4; ++l) {
    out[(size_t)l * 4198401u + p] =
        Cm2l[l * 4 + 0] * pm[0] + Cm2l[l * 4 + 1] * pm[1] +
        Cm2l[l * 4 + 2] * pm[2] + Cm2l[l * 4 + 3] * pm[3];
  }
}

extern "C" void kernel_launch(void* const* d_in, const int* in_sizes, int n_in,
                              void* d_out, int out_size, void* d_ws, size_t ws_size,
                              hipStream_t stream) {
  const float* q     = (const float*)d_in[0];   // [4,2047,2047]
  const float* Cl2m  = (const float*)d_in[1];   // [4,4]
  const float* Cm2l  = (const float*)d_in[2];   // [4,4]
  const float* H     = (const float*)d_in[3];   // [4,2047,2047]
  const float* hom   = (const float*)d_in[4];   // [4,2049,2049]
  const float* hmean = (const float*)d_in[5];   // [4]
  float* out = (float*)d_out;

  char* ws = (char*)d_ws;
  unsigned short* P  = (unsigned short*)ws;                    // 33,554,432 B
  unsigned short* Q  = (unsigned short*)(ws + 33554432u);      // 33,554,432 B
  unsigned short* Sb = (unsigned short*)(ws + 67108864u);      //  8,388,608 B
  float* sums        = (float*)(ws + 75497472u);               //        16 B

  dst_kernel<<<16384, 256, 0, stream>>>(Sb);
  mix_kernel<<<16384, 256, 0, stream>>>(q, Cl2m, P);
  hipMemsetAsync(sums, 0, 16, stream);

  // Q1 = P * S            (DST along y)
  gemm256<0><<<256, 512, 0, stream>>>(P, Sb, Q, nullptr, nullptr);
  transpose_bf16<<<dim3(32, 32, 4), 256, 0, stream>>>(Q, P);
  // Q2 = (P * S) / H      (DST along x; H symmetric)
  gemm256<1><<<256, 512, 0, stream>>>(P, Sb, Q, H, nullptr);
  // P2 = Q2 * S           (inverse DST step 1)
  gemm256<0><<<256, 512, 0, stream>>>(Q, Sb, P, nullptr, nullptr);
  transpose_bf16<<<dim3(32, 32, 4), 256, 0, stream>>>(P, Q);
  // T5 = Q3 * S (+ per-mode sum for mean correction)
  gemm256<2><<<256, 512, 0, stream>>>(Q, Sb, P, nullptr, sums);

  final_kernel<<<16401, 256, 0, stream>>>(P, hom, hmean, Cm2l, sums, out);
}

// Round 3
// 374.837 us; speedup vs baseline: 1.3200x; 1.0564x over previous
//
#include <hip/hip_runtime.h>

// DST-I spectral Helmholtz solver, NZ=4, NX=NY=2048.
// psi = Cm2l · [ S (S (Cl2m·q) S ⊘ H) S  + alpha·homsol ],  S = DST-I matrix (symmetric, orthonormal)
// GEMMs: 256x256 8-wave, m201 cadence (reads -> barrier -> lgkm -> MFMA), counted vmcnt.

typedef __attribute__((ext_vector_type(8))) short bf16x8;
typedef __attribute__((ext_vector_type(4))) float f32x4;
typedef __attribute__((ext_vector_type(8))) unsigned short ushort8;

#define LDS_SPACE __attribute__((address_space(3)))
#define GLB_SPACE __attribute__((address_space(1)))

__device__ __forceinline__ void gld_lds16(const unsigned short* g, unsigned short* l) {
  __builtin_amdgcn_global_load_lds((const GLB_SPACE void*)g, (LDS_SPACE void*)l, 16, 0, 0);
}

__device__ __forceinline__ bf16x8 ds_read128(const void* p) {
  bf16x8 r;
  const LDS_SPACE char* lp = (const LDS_SPACE char*)p;
  asm volatile("ds_read_b128 %0, %1" : "=v"(r) : "v"(lp));
  return r;
}

__device__ __forceinline__ unsigned short f2b(float f) {
  union { float f; unsigned u; } v; v.f = f;
  unsigned r = (v.u + 0x7fffu + ((v.u >> 16) & 1u)) >> 16;  // RNE
  return (unsigned short)r;
}
__device__ __forceinline__ float b2f(unsigned short u) {
  union { unsigned u; float f; } v; v.u = ((unsigned)u) << 16;
  return v.f;
}

// ---- DST-I matrix, padded to 2048x2048 (row/col 2047 zero), bf16 ----
__global__ __launch_bounds__(256)
void dst_kernel(unsigned short* __restrict__ Sb) {
  const int idx = blockIdx.x * 256 + threadIdx.x;
  const int j = idx & 2047, i = idx >> 11;
  float v = 0.f;
  if (i < 2047 && j < 2047) {
    const int ph = ((i + 1) * (j + 1)) & 4095;  // exact phase mod 2*pi
    v = 0.03125f * sinf(3.14159265358979323846f * (float)ph * (1.0f / 2048.0f));
  }
  Sb[idx] = f2b(v);
}

// ---- layer->mode mix: P[m] = sum_l Cl2m[m,l] q[l], padded to 2048^2, bf16 ----
__global__ __launch_bounds__(256)
void mix_kernel(const float* __restrict__ q, const float* __restrict__ Cl2m,
                unsigned short* __restrict__ P) {
  const int idx = blockIdx.x * 256 + threadIdx.x;
  const int y = idx & 2047, x = idx >> 11;
  float c[16];
#pragma unroll
  for (int i = 0; i < 16; ++i) c[i] = Cl2m[i];
  float v0 = 0.f, v1 = 0.f, v2 = 0.f, v3 = 0.f;
  if (x < 2047 && y < 2047) {
    const size_t o = (size_t)x * 2047 + y;
    const float q0 = q[o];
    const float q1 = q[o + 4190209u];
    const float q2 = q[o + 2u * 4190209u];
    const float q3 = q[o + 3u * 4190209u];
    v0 = c[0]  * q0 + c[1]  * q1 + c[2]  * q2 + c[3]  * q3;
    v1 = c[4]  * q0 + c[5]  * q1 + c[6]  * q2 + c[7]  * q3;
    v2 = c[8]  * q0 + c[9]  * q1 + c[10] * q2 + c[11] * q3;
    v3 = c[12] * q0 + c[13] * q1 + c[14] * q2 + c[15] * q3;
  }
  P[idx]                 = f2b(v0);
  P[idx + 4194304u]      = f2b(v1);
  P[idx + 2u * 4194304u] = f2b(v2);
  P[idx + 3u * 4194304u] = f2b(v3);
}

// ---- batched per-mode 2048x2048 bf16 transpose (64x64 LDS tiles) ----
__global__ __launch_bounds__(256)
void transpose_bf16(const unsigned short* __restrict__ in, unsigned short* __restrict__ out) {
  __shared__ unsigned short tile[64][65];
  const size_t pb = (size_t)blockIdx.z * (2048u * 2048u);
  const unsigned short* ip = in + pb;
  unsigned short* op = out + pb;
  const int r0 = blockIdx.y * 64, c0 = blockIdx.x * 64;
  const int t = threadIdx.x;
  const int rr = t >> 3;
  const int cc = (t & 7) * 8;
#pragma unroll
  for (int ch = 0; ch < 2; ++ch) {
    const int r = ch * 32 + rr;
    ushort8 v = *(const ushort8*)&ip[(size_t)(r0 + r) * 2048 + c0 + cc];
#pragma unroll
    for (int j = 0; j < 8; ++j) tile[r][cc + j] = v[j];
  }
  __syncthreads();
#pragma unroll
  for (int ch = 0; ch < 2; ++ch) {
    const int r = ch * 32 + rr;
    ushort8 v;
#pragma unroll
    for (int j = 0; j < 8; ++j) v[j] = tile[cc + j][r];
    *(ushort8*)&op[(size_t)(c0 + r) * 2048 + r0 + cc] = v;
  }
}

// ---- GEMM: C[8192x2048] = A[8192x2048] * S (S symmetric), 256^2 tile, 8 waves ----
// EPI 0: write bf16. EPI 1: divide by H (interior), write bf16. EPI 2: write bf16 + per-mode sum.
#define MFMA_BF16 __builtin_amdgcn_mfma_f32_16x16x32_bf16

template <int EPI>
__global__ __launch_bounds__(512, 2)
void gemm256(const unsigned short* __restrict__ A, const unsigned short* __restrict__ S,
             unsigned short* __restrict__ Cb, const float* __restrict__ H,
             float* __restrict__ sums) {
  __shared__ __align__(16) char lds[131072];  // 2 buffers x (A 32KB + B 32KB)
  const int bid = blockIdx.x;
  const int swz = (bid & 7) * 32 + (bid >> 3);      // XCD-bijective (256 % 8 == 0)
  const int bm = swz >> 3, bn = swz & 7;
  const int tid = threadIdx.x;
  const int lane = tid & 63, wave = tid >> 6;
  const int wr = wave >> 2, wc = wave & 3;          // 2 x 4 wave grid
  const int lr = lane & 15, kg = lane >> 4;

  const unsigned short* gA = A + (size_t)bm * 256 * 2048;
  const unsigned short* gB = S + (size_t)bn * 256 * 2048;

  // staging geometry: physical 16B slot ps = tid + i*512; row = ps>>3;
  // global col16 = (ps&7) ^ (row&7)  (inverse of the read-side XOR swizzle)
  const int row0 = tid >> 3;
  const int slot = (tid & 7) ^ (row0 & 7);

  auto stage = [&](int kt, int c) {
    char* lc = lds + c * 65536;
    const size_t ko = (size_t)kt * 64 + slot * 8;
#pragma unroll
    for (int i = 0; i < 4; ++i)
      gld_lds16(gA + (size_t)(row0 + i * 64) * 2048 + ko,
                (unsigned short*)(lc + (tid + i * 512) * 16));
#pragma unroll
    for (int i = 0; i < 4; ++i)
      gld_lds16(gB + (size_t)(row0 + i * 64) * 2048 + ko,
                (unsigned short*)(lc + 32768 + (tid + i * 512) * 16));
  };

  f32x4 acc[8][4];
#pragma unroll
  for (int m = 0; m < 8; ++m)
#pragma unroll
    for (int n = 0; n < 4; ++n) acc[m][n] = (f32x4){0.f, 0.f, 0.f, 0.f};

  stage(0, 0);
  stage(1, 1);

  const int arow = wr * 128 + lr;   // + m*16
  const int brow = wc * 64 + lr;    // + n*16
  const int x7 = lr & 7;            // (row & 7) for the read-side XOR swizzle

  for (int t = 0; t < 32; ++t) {
    const char* la = lds + (t & 1) * 65536;
    const char* lb = la + 32768;
    // own tile-t loads are the 8 oldest; they were issued a full iteration ago
    if (t < 31) asm volatile("s_waitcnt vmcnt(8)" ::: "memory");
    else        asm volatile("s_waitcnt vmcnt(0)" ::: "memory");
    __builtin_amdgcn_s_barrier();   // after this, ALL waves' tile-t loads landed

    bf16x8 al[4][2], ah[4][2], bl[2][2], bh[2][2];

    // ==== E1: issue al(8)+bl(4) -> barrier -> wait -> MFMA Q1 (m0-3, n0-1)
#pragma unroll
    for (int m = 0; m < 4; ++m)
#pragma unroll
      for (int ks = 0; ks < 2; ++ks)
        al[m][ks] = ds_read128(la + (arow + m * 16) * 128 + (((ks * 4 + kg) ^ x7) << 4));
#pragma unroll
    for (int n = 0; n < 2; ++n)
#pragma unroll
      for (int ks = 0; ks < 2; ++ks)
        bl[n][ks] = ds_read128(lb + (brow + n * 16) * 128 + (((ks * 4 + kg) ^ x7) << 4));
    __builtin_amdgcn_s_barrier();
    asm volatile("s_waitcnt lgkmcnt(0)" ::: "memory");
    __builtin_amdgcn_sched_barrier(0);
    __builtin_amdgcn_s_setprio(1);
#pragma unroll
    for (int ks = 0; ks < 2; ++ks)
#pragma unroll
      for (int m = 0; m < 4; ++m)
#pragma unroll
        for (int n = 0; n < 2; ++n)
          acc[m][n] = MFMA_BF16(al[m][ks], bl[n][ks], acc[m][n], 0, 0, 0);
    __builtin_amdgcn_s_setprio(0);

    // ==== E2: issue bh(4) then ah(8) -> barrier -> wait bh only -> MFMA Q2 (m0-3, n2-3)
#pragma unroll
    for (int n = 0; n < 2; ++n)
#pragma unroll
      for (int ks = 0; ks < 2; ++ks)
        bh[n][ks] = ds_read128(lb + (brow + (n + 2) * 16) * 128 + (((ks * 4 + kg) ^ x7) << 4));
#pragma unroll
    for (int m = 0; m < 4; ++m)
#pragma unroll
      for (int ks = 0; ks < 2; ++ks)
        ah[m][ks] = ds_read128(la + (arow + (m + 4) * 16) * 128 + (((ks * 4 + kg) ^ x7) << 4));
    __builtin_amdgcn_s_barrier();
    asm volatile("s_waitcnt lgkmcnt(8)" ::: "memory");   // bh done; ah may fly
    __builtin_amdgcn_sched_barrier(0);
    __builtin_amdgcn_s_setprio(1);
#pragma unroll
    for (int ks = 0; ks < 2; ++ks)
#pragma unroll
      for (int m = 0; m < 4; ++m)
#pragma unroll
        for (int n = 0; n < 2; ++n)
          acc[m][n + 2] = MFMA_BF16(al[m][ks], bh[n][ks], acc[m][n + 2], 0, 0, 0);
    __builtin_amdgcn_s_setprio(0);

    // ==== E3: no reads -> barrier -> wait ah -> MFMA Q3+Q4 (m4-7, all n)
    __builtin_amdgcn_s_barrier();
    asm volatile("s_waitcnt lgkmcnt(0)" ::: "memory");
    __builtin_amdgcn_sched_barrier(0);
    __builtin_amdgcn_s_setprio(1);
#pragma unroll
    for (int ks = 0; ks < 2; ++ks)
#pragma unroll
      for (int m = 0; m < 4; ++m)
#pragma unroll
        for (int n = 0; n < 2; ++n)
          acc[m + 4][n + 2] = MFMA_BF16(ah[m][ks], bh[n][ks], acc[m + 4][n + 2], 0, 0, 0);
#pragma unroll
    for (int ks = 0; ks < 2; ++ks)
#pragma unroll
      for (int m = 0; m < 4; ++m)
#pragma unroll
        for (int n = 0; n < 2; ++n)
          acc[m + 4][n] = MFMA_BF16(ah[m][ks], bl[n][ks], acc[m + 4][n], 0, 0, 0);
    __builtin_amdgcn_s_setprio(0);

    // prefetch 2 tiles ahead into the buffer this iteration just finished reading
    if (t < 30) stage(t + 2, t & 1);
  }

  // ---- epilogue: C row = kg*4+j within fragment, col = lr
  float ssum = 0.f;
#pragma unroll
  for (int m = 0; m < 8; ++m) {
#pragma unroll
    for (int n = 0; n < 4; ++n) {
      const int col = bn * 256 + wc * 64 + n * 16 + lr;
#pragma unroll
      for (int j = 0; j < 4; ++j) {
        const int gr = bm * 256 + wr * 128 + m * 16 + kg * 4 + j;
        const float v = acc[m][n][j];
        if (EPI == 1) {
          const int i = gr & 2047;
          float o = 0.f;
          if (i < 2047 && col < 2047)
            o = v / H[((size_t)(gr >> 11) * 2047 + i) * 2047 + col];
          Cb[(size_t)gr * 2048 + col] = f2b(o);
        } else {
          Cb[(size_t)gr * 2048 + col] = f2b(v);
          if (EPI == 2) ssum += v;
        }
      }
    }
  }
  if (EPI == 2) {
#pragma unroll
    for (int off = 32; off > 0; off >>= 1) ssum += __shfl_xor(ssum, off);
    if (lane == 0) atomicAdd(&sums[bm >> 3], ssum);
  }
}

// ---- final: un-pad, homogeneous correction, mode->layer mix ----
__global__ __launch_bounds__(256)
void final_kernel(const unsigned short* __restrict__ T5, const float* __restrict__ homsol,
                  const float* __restrict__ hm, const float* __restrict__ Cm2l,
                  const float* __restrict__ sums, float* __restrict__ out) {
  const int p = blockIdx.x * 256 + threadIdx.x;
  if (p >= 2049 * 2049) return;
  const int x = p / 2049, y = p - x * 2049;
  const bool interior = (x >= 1) && (x <= 2047) && (y >= 1) && (y <= 2047);
  float pm[4];
#pragma unroll
  for (int m = 0; m < 4; ++m) {
    float inner = 0.f;
    if (interior) inner = b2f(T5[(size_t)m * 4194304u + (size_t)(x - 1) * 2048 + (y - 1)]);
    const float alpha = -(sums[m] * (1.0f / 4194304.0f)) / hm[m];
    pm[m] = inner + alpha * homsol[(size_t)m * 4198401u + p];
  }
#pragma unroll
  for (int l = 0; l < 4; ++l) {
    out[(size_t)l * 4198401u + p] =
        Cm2l[l * 4 + 0] * pm[0] + Cm2l[l * 4 + 1] * pm[1] +
        Cm2l[l * 4 + 2] * pm[2] + Cm2l[l * 4 + 3] * pm[3];
  }
}

extern "C" void kernel_launch(void* const* d_in, const int* in_sizes, int n_in,
                              void* d_out, int out_size, void* d_ws, size_t ws_size,
                              hipStream_t stream) {
  const float* q     = (const float*)d_in[0];   // [4,2047,2047]
  const float* Cl2m  = (const float*)d_in[1];   // [4,4]
  const float* Cm2l  = (const float*)d_in[2];   // [4,4]
  const float* H     = (const float*)d_in[3];   // [4,2047,2047]
  const float* hom   = (const float*)d_in[4];   // [4,2049,2049]
  const float* hmean = (const float*)d_in[5];   // [4]
  float* out = (float*)d_out;

  char* ws = (char*)d_ws;
  unsigned short* P  = (unsigned short*)ws;                    // 33,554,432 B
  unsigned short* Q  = (unsigned short*)(ws + 33554432u);      // 33,554,432 B
  unsigned short* Sb = (unsigned short*)(ws + 67108864u);      //  8,388,608 B
  float* sums        = (float*)(ws + 75497472u);               //        16 B

  dst_kernel<<<16384, 256, 0, stream>>>(Sb);
  mix_kernel<<<16384, 256, 0, stream>>>(q, Cl2m, P);
  hipMemsetAsync(sums, 0, 16, stream);

  // Q1 = P * S            (DST along y)
  gemm256<0><<<256, 512, 0, stream>>>(P, Sb, Q, nullptr, nullptr);
  transpose_bf16<<<dim3(32, 32, 4), 256, 0, stream>>>(Q, P);
  // Q2 = (P * S) / H      (DST along x; H symmetric)
  gemm256<1><<<256, 512, 0, stream>>>(P, Sb, Q, H, nullptr);
  // P2 = Q2 * S           (inverse DST step 1)
  gemm256<0><<<256, 512, 0, stream>>>(Q, Sb, P, nullptr, nullptr);
  transpose_bf16<<<dim3(32, 32, 4), 256, 0, stream>>>(P, Q);
  // T5 = Q3 * S (+ per-mode sum for mean correction)
  gemm256<2><<<256, 512, 0, stream>>>(Q, Sb, P, nullptr, sums);

  final_kernel<<<16401, 256, 0, stream>>>(P, hom, hmean, Cm2l, sums, out);
}